// Round 17
// baseline (228.045 us; speedup 1.0000x reference)
//
#include <hip/hip_runtime.h>
#include <hip/hip_bf16.h>

#define KK 5
constexpr int N0 = 78400;     // B*28*28
constexpr int E0 = 627200;    // N0*8
constexpr int N1 = 19600;     // B*14*14
constexpr int E1 = 156800;    // N1*8
constexpr int C1 = 32, C2 = 64;
constexpr int BSZ = 100;
constexpr int FC1_IN = 3136, FC1_OUT = 512;
constexpr int NKEYS = 98000;  // N0 + N1 global node keys
constexpr int NCOARSE = 383;  // coarse buckets of 256 keys
constexpr int CAPB = 2400;    // bucket capacity: Poisson(2048) + 7.7 sigma
constexpr int KEXT = 832;     // 800 tap-space + 32 root channels
constexpr int ULS = 836;      // LDS fp32 U row stride
constexpr int UBS = 856;      // LDS bf16 U row stride (ushorts)
constexpr int CH2 = 160;      // conv2 edge staging chunk (block avg ~64)
constexpr int CH1 = 640;      // conv1 edge staging chunk (block avg ~448)

typedef __attribute__((ext_vector_type(8))) short bf16x8;
typedef __attribute__((ext_vector_type(4))) float f32x4;

__device__ __forceinline__ unsigned short f2bf(float f) {
    union { float f; unsigned u; } v; v.f = f;
    unsigned u = v.u;
    unsigned r = (u + 0x7FFF + ((u >> 16) & 1)) >> 16;   // RNE
    return (unsigned short)r;
}

__device__ __forceinline__ void taps4(float px, float py,
                                      int& a00, int& a01, int& a10, int& a11,
                                      float& fx, float& fy) {
    float kfx = floorf(px), kfy = floorf(py);
    fx = px - kfx; fy = py - kfy;
    int k0x = min(max((int)kfx, 0), KK - 1);
    int k0y = min(max((int)kfy, 0), KK - 1);
    int k1x = min(k0x + 1, KK - 1), k1y = min(k0y + 1, KK - 1);
    a00 = k0x * KK + k0y; a01 = k0x * KK + k1y;
    a10 = k1x * KK + k0y; a11 = k1x * KK + k1y;
}

// ---- sort A: LDS-histogram coarse binning; packed {id | lowkey<<20} runs ----
__global__ void coarse_bin(const int* __restrict__ ei0, const int* __restrict__ ei1,
                           int* __restrict__ gcur, int* __restrict__ pk) {
    __shared__ int hist[NCOARSE];
    __shared__ int gbase[NCOARSE];
    int t = threadIdx.x;               // 512 threads
    for (int i = t; i < NCOARSE; i += 512) hist[i] = 0;
    __syncthreads();
    int e0b = blockIdx.x * 4096;
    int ids[8], keys[8], rnk[8];
#pragma unroll
    for (int j = 0; j < 8; j++) {
        int e = e0b + t + j * 512;
        int gk = -1, id = 0;
        if (e < E0) { gk = ei0[E0 + e]; id = e; }
        else if (e < E0 + E1) { int el = e - E0; gk = N0 + ei1[E1 + el]; id = el; }
        ids[j] = id; keys[j] = gk;
    }
#pragma unroll
    for (int j = 0; j < 8; j++)
        if (keys[j] >= 0) rnk[j] = atomicAdd(&hist[keys[j] >> 8], 1);  // native ds_add
    __syncthreads();
    for (int i = t; i < NCOARSE; i += 512)
        gbase[i] = hist[i] ? atomicAdd(&gcur[i], hist[i]) : 0;
    __syncthreads();
#pragma unroll
    for (int j = 0; j < 8; j++) {
        if (keys[j] >= 0) {
            int b = keys[j] >> 8;
            int p = gbase[b] + rnk[j];
            if (p < CAPB) pk[b * CAPB + p] = ids[j] | ((keys[j] & 255) << 20);
        }
    }
}

// ---- sort B: scan 383 bucket counts -> dense bases ----
__global__ void tiny_scan(const int* __restrict__ gcur, int* __restrict__ db,
                          int* __restrict__ off) {
    __shared__ int tmp[NCOARSE];
    int t = threadIdx.x;   // 512
    if (t < NCOARSE) tmp[t] = min(gcur[t], CAPB);
    __syncthreads();
    if (t == 0) {
        int s = 0;
        for (int i = 0; i < NCOARSE; i++) { int c = tmp[i]; tmp[i] = s; s += c; }
    }
    __syncthreads();
    if (t < NCOARSE) db[t] = tmp[t];
    if (t == 0) off[NKEYS] = E0 + E1;
}

// ---- sort C: per-bucket LDS counting sort -> dense idxx + off ----
__global__ void fine_sort(const int* __restrict__ pk, const int* __restrict__ gcur,
                          const int* __restrict__ db,
                          int* __restrict__ idxx, int* __restrict__ off) {
    __shared__ int ent[CAPB];
    __shared__ int rnk[CAPB];
    __shared__ int h2[256];
    __shared__ int sc[256];
    int b = blockIdx.x, t = threadIdx.x;   // 256 threads
    int cb = min(gcur[b], CAPB);
    int base = db[b];
    h2[t] = 0;
    __syncthreads();
    for (int i = t; i < cb; i += 256) {
        int v = pk[b * CAPB + i];
        ent[i] = v;
        rnk[i] = atomicAdd(&h2[(v >> 20) & 255], 1);   // native ds_add
    }
    __syncthreads();
    int v0 = h2[t];
    sc[t] = v0;
    __syncthreads();
    for (int d = 1; d < 256; d <<= 1) {
        int add = (t >= d) ? sc[t - d] : 0;
        __syncthreads();
        sc[t] += add;
        __syncthreads();
    }
    int excl = sc[t] - v0;
    __syncthreads();
    sc[t] = excl;
    __syncthreads();
    int n = (b << 8) + t;
    if (n < NKEYS) off[n] = base + excl;
    for (int i = t; i < cb; i += 256) {
        int v = ent[i];
        idxx[base + sc[(v >> 20) & 255] + rnk[i]] = v & 0xFFFFF;
    }
}

// ---- conv1 + pool1 fused: block = 2 image rows (56 nodes). Cooperative edge
//      staging (one latency round), quadrant-private LDS tap slices, h1 kept
//      in LDS and pooled in-kernel -> p1. No atomics, no h1 global traffic. ----
__global__ __launch_bounds__(256, 4)
void conv1_pool(const int* __restrict__ idxx, const int* __restrict__ off,
                const float* __restrict__ x, const int* __restrict__ ei0,
                const float* __restrict__ ps0, const float* __restrict__ W1,
                const float* __restrict__ root, const float* __restrict__ bias,
                float* __restrict__ p1) {
    __shared__ float S4[224 * 25];    // 22.4 KB quadrant slices; h1 tile aliases
    __shared__ float Sr[56 * 25];     // 5.6 KB reduced
    __shared__ float exv[CH1], efx[CH1], efy[CH1];
    __shared__ int   emt[CH1];        // 10.2 KB staging
    float* h1t = S4;                  // 1792 floats, reused after reduce
    int t = threadIdx.x;
    int bb = blockIdx.x;              // 1400 blocks; nodes bb*56 .. +55
    int n0 = bb * 56;
    int q = t & 3, nl = t >> 2;       // nl 0..63 (only <56 active)
    bool actN = nl < 56;
    int n = n0 + (actN ? nl : 0);
    float* sp = S4 + (actN ? (nl * 4 + q) : 0) * 25;
    for (int i = t; i < 224 * 25; i += 256) S4[i] = 0.f;
    int e0 = off[n0], e1 = off[n0 + 56];
    int my0 = off[n], my1 = off[n + 1];
    for (int base = e0; base < e1; base += CH1) {
        int nE = min(e1 - base, CH1);
        __syncthreads();
        for (int j = t; j < nE; j += 256) {
            int e = idxx[base + j];
            int src = ei0[e];
            int a00, a01, a10, a11; float fx, fy;
            taps4(ps0[2 * e] * (KK - 1), ps0[2 * e + 1] * (KK - 1),
                  a00, a01, a10, a11, fx, fy);
            emt[j] = a00 | (a01 << 5) | (a10 << 10) | (a11 << 15);
            efx[j] = fx; efy[j] = fy;
            exv[j] = x[src];
        }
        __syncthreads();
        if (actN) {
            int r0 = max(my0 - base, 0), r1 = min(my1 - base, nE);
            for (int p = r0 + q; p < r1; p += 4) {
                float xv = exv[p]; int m = emt[p];
                float fx = efx[p], fy = efy[p];
                float gx = 1.f - fx, gy = 1.f - fy;
                sp[m & 31]         += gx * gy * xv;
                sp[(m >> 5) & 31]  += gx * fy * xv;
                sp[(m >> 10) & 31] += fx * gy * xv;
                sp[(m >> 15) & 31] += fx * fy * xv;
            }
        }
    }
    __syncthreads();
    for (int i2 = t; i2 < 56 * 25; i2 += 256) {
        int n2 = i2 / 25, a = i2 - n2 * 25;
        Sr[i2] = S4[(n2 * 4 + 0) * 25 + a] + S4[(n2 * 4 + 1) * 25 + a] +
                 S4[(n2 * 4 + 2) * 25 + a] + S4[(n2 * 4 + 3) * 25 + a];
    }
    __syncthreads();
    {   // h1 for 56 nodes x 32 ch -> LDS tile (aliases S4; reads of S4 done)
        int o = t & 31, ng = t >> 5;  // ng 0..7, 7 nodes each
        float w1c[25];
#pragma unroll
        for (int a = 0; a < 25; a++) w1c[a] = W1[a * C1 + o];
        float ro = root[o], bo = bias[o];
        for (int j2 = 0; j2 < 7; j2++) {
            int nl2 = ng * 7 + j2;
            int n2 = n0 + nl2;
            float acc = 0.f;
#pragma unroll
            for (int a = 0; a < 25; a++) acc += Sr[nl2 * 25 + a] * w1c[a];
            float invd = 1.f / fmaxf((float)(off[n2 + 1] - off[n2]), 1.f);
            float v = acc * invd + x[n2] * ro + bo;
            h1t[nl2 * 32 + o] = v > 0.f ? v : expm1f(v);
        }
    }
    __syncthreads();
    // pool 2x2: 14 pooled cols x 32 ch = 448 outputs; rows 0 and 1 of tile
    for (int i2 = t; i2 < 448; i2 += 256) {
        int o2 = i2 & 31, pc = i2 >> 5;
        float m0 = h1t[(2 * pc) * 32 + o2],      m1 = h1t[(2 * pc + 1) * 32 + o2];
        float m2 = h1t[(28 + 2 * pc) * 32 + o2], m3 = h1t[(28 + 2 * pc + 1) * 32 + o2];
        p1[(bb * 14 + pc) * C1 + o2] = fmaxf(fmaxf(m0, m1), fmaxf(m2, m3));
    }
}

// ---- merged weight prep: wt1 transpose tiles + w2t (blockIdx.x == 49) ----
__global__ void prep_weights(const float* __restrict__ w, const float* __restrict__ W2,
                             const float* __restrict__ root2,
                             unsigned short* __restrict__ wt1,
                             unsigned short* __restrict__ w2t) {
    if (blockIdx.x == 49) {          // 8 blocks (y=0..7): w2t, 6656 elements each
        int base = blockIdx.y * 6656;
        for (int i = threadIdx.x; i < 6656; i += 256) {
            int idx = base + i;
            int o = idx / KEXT, k = idx - o * KEXT;
            float v = (k < 800) ? W2[k * 64 + o] : root2[(k - 800) * 64 + o];
            w2t[idx] = f2bf(v);
        }
        return;
    }
    __shared__ unsigned short tile[64 * 66];
    int t = threadIdx.x;
    int k0 = blockIdx.x * 64, j0 = blockIdx.y * 64;
    int jj = t & 63, ks = t >> 6;
    for (int kk = ks; kk < 64; kk += 4)
        tile[kk * 66 + jj] = f2bf(w[(k0 + kk) * FC1_OUT + j0 + jj]);
    __syncthreads();
    int kk = t & 63, js = t >> 6;
    for (int j2 = js; j2 < 64; j2 += 4)
        wt1[(j0 + j2) * FC1_IN + k0 + kk] = tile[kk * 66 + j2];
}

// ---- conv2 fused (MFMA): 8 nodes/block, 5 blocks/CU.
//  Phase1: wave-uniform trip count (max of the two half-wave groups, not sum)
//  with predicated body; Phase1.5: single fp32->bf16 pass (invd folded);
//  Phase2: MFMA with direct b128 bf16 A-frag reads. ----
__global__ __launch_bounds__(256, 5)
void conv2_fused(const float* __restrict__ p1, const int* __restrict__ idxx,
                 const int* __restrict__ off, const int* __restrict__ ei1,
                 const float* __restrict__ ps1,
                 const unsigned short* __restrict__ w2t,
                 const float* __restrict__ b2, float* __restrict__ h2) {
    __shared__ float Ul[8 * ULS];           // 26.8 KB (bf16 view aliases this)
    __shared__ int   es[CH2];
    __shared__ int   et[CH2];
    __shared__ float efx[CH2], efy[CH2];
    unsigned short* Ub = (unsigned short*)Ul;
    int t = threadIdx.x;
    int nb = blockIdx.x * 8;
    int i = t & 31, g = t >> 5;             // channel lane, group = node 0..7
    float* up = Ul + g * ULS;
#pragma unroll
    for (int a = 0; a < 25; a++) up[a * 32 + i] = 0.f;
    up[800 + i] = p1[(nb + g) * C1 + i];
    int e0 = off[N0 + nb], e1 = off[N0 + nb + 8];
    int my0 = off[N0 + nb + g], my1 = off[N0 + nb + g + 1];
    for (int base = e0; base < e1; base += CH2) {
        int nE = min(e1 - base, CH2);
        __syncthreads();
        for (int j = t; j < nE; j += 256) {
            int e = idxx[base + j];
            es[j] = ei1[e];
            int a00, a01, a10, a11; float fx, fy;
            taps4(ps1[2 * e] * (KK - 1), ps1[2 * e + 1] * (KK - 1),
                  a00, a01, a10, a11, fx, fy);
            et[j] = a00 | (a01 << 5) | (a10 << 10) | (a11 << 15);
            efx[j] = fx; efy[j] = fy;
        }
        __syncthreads();
        int r0 = max(my0 - base, 0);
        int r1 = min(my1 - base, nE);
        int myT = max(r1 - r0, 0);
        int m64 = max(myT, __shfl_xor(myT, 32));   // wave-uniform trip count
#pragma unroll 2
        for (int jj = 0; jj < m64; jj++) {
            int j = r0 + jj;
            bool act = j < r1;
            int ji = act ? j : 0;
            int src = es[ji]; int m = et[ji];
            float fx = efx[ji], fy = efy[ji];
            float xv = p1[src * C1 + i];    // coalesced 128B per group
            if (act) {
                float gx = 1.f - fx, gy = 1.f - fy;
                up[(m & 31) * 32 + i]         += gx * gy * xv;
                up[((m >> 5) & 31) * 32 + i]  += gx * fy * xv;
                up[((m >> 10) & 31) * 32 + i] += fx * gy * xv;
                up[((m >> 15) & 31) * 32 + i] += fx * fy * xv;
            }
        }
    }
    __syncthreads();
    // phase 1.5: fp32 -> bf16 once (invd folded into tap part)
    {
        int g2 = t >> 5, ks = (t & 31) * 26;
        int dgc = off[N0 + nb + g2 + 1] - off[N0 + nb + g2];
        float invd = 1.f / fmaxf((float)dgc, 1.f);
        const float* srcp = Ul + g2 * ULS + ks;
        float rv[26];
#pragma unroll
        for (int j = 0; j < 26; j++) {
            float v = srcp[j];
            rv[j] = (ks + j < 800) ? v * invd : v;
        }
        __syncthreads();
        unsigned* dstp = (unsigned*)(Ub + g2 * UBS + ks);
#pragma unroll
        for (int j = 0; j < 13; j++) {
            unsigned lo = f2bf(rv[2 * j]), hi = f2bf(rv[2 * j + 1]);
            dstp[j] = lo | (hi << 16);
        }
    }
    __syncthreads();
    // phase 2: MFMA. D[node=quad*4+r][o=lane&15]; A rows 8-15 alias 0-7
    int wv = t >> 6, lane = t & 63, quad = lane >> 4, lrow = lane & 15;
    f32x4 acc = {0.f, 0.f, 0.f, 0.f};
    int nodeA = lrow & 7;
    const unsigned short* bbase = w2t + (wv * 16 + lrow) * KEXT;
    const unsigned short* abase = Ub + nodeA * UBS;
#pragma unroll
    for (int kc = 0; kc < 26; kc++) {
        bf16x8 a = *(const bf16x8*)(abase + kc * 32 + quad * 8);
        bf16x8 b = *(const bf16x8*)(bbase + kc * 32 + quad * 8);
        acc = __builtin_amdgcn_mfma_f32_16x16x32_bf16(a, b, acc, 0, 0, 0);
    }
    if (quad < 2) {
        int o = wv * 16 + lrow;
        float bo = b2[o];
#pragma unroll
        for (int r = 0; r < 4; r++) {
            int node = quad * 4 + r;
            float v = acc[r] + bo;
            v = v > 0.f ? v : expm1f(v);
            h2[(nb + node) * C2 + o] = v;
        }
    }
}

// ---- pool2 -> bf16 [112 x 3136], rows 100..111 zeroed (M-pad for MFMA) ----
__global__ void pool2b(const float* __restrict__ h2, unsigned short* __restrict__ p2b) {
    int idx = blockIdx.x * blockDim.x + threadIdx.x;
    if (idx >= 112 * FC1_IN) return;
    if (idx >= 100 * FC1_IN) { p2b[idx] = 0; return; }
    int o = idx & 63; int t2 = idx >> 6;
    int c = t2 % 14; int r = (t2 / 14) % 14; int b = t2 / 196;
    const float* base = h2 + (((b * 28 + 2 * r) * 28 + 2 * c) * C2 + o);
    float m = fmaxf(fmaxf(base[0], base[C2]),
                    fmaxf(base[28 * C2], base[28 * C2 + C2]));
    p2b[idx] = f2bf(m);
}

// ---- fc1 MFMA: [112,3136]bf16 @ wt1^T -> z1p fp32 partials (2 kz). ----
__global__ void gemm_fc1(const unsigned short* __restrict__ p2b,
                         const unsigned short* __restrict__ wt1,
                         float* __restrict__ z1p) {
    constexpr int AS = 232;
    __shared__ unsigned short as_[16 * AS];
    int t = threadIdx.x;
    int jt = blockIdx.x, mt = blockIdx.y, kz = blockIdx.z;
    int wv = t >> 6, lane = t & 63, quad = lane >> 4, lrow = lane & 15;
    int m0 = mt * 16;
    int kbase = kz * 1568;
    const unsigned short* bbase = wt1 + (jt * 64 + wv * 16 + lrow) * FC1_IN + kbase;
    f32x4 acc = {0.f, 0.f, 0.f, 0.f};
    for (int ch = 0; ch < 7; ch++) {
        __syncthreads();
        for (int slot = t; slot < 448; slot += 256) {
            int r = slot / 28, c = slot - (slot / 28) * 28;
            *(uint4*)(as_ + r * AS + c * 8) =
                *(const uint4*)(p2b + (m0 + r) * FC1_IN + kbase + ch * 224 + c * 8);
        }
        __syncthreads();
        const unsigned short* ab = as_ + lrow * AS;
        const unsigned short* bb = bbase + ch * 224;
#pragma unroll
        for (int kk = 0; kk < 7; kk++) {
            bf16x8 a = *(const bf16x8*)(ab + kk * 32 + quad * 8);
            bf16x8 b = *(const bf16x8*)(bb + kk * 32 + quad * 8);
            acc = __builtin_amdgcn_mfma_f32_16x16x32_bf16(a, b, acc, 0, 0, 0);
        }
    }
    int n = jt * 64 + wv * 16 + lrow;
#pragma unroll
    for (int r = 0; r < 4; r++) {
        int m = m0 + quad * 4 + r;
        z1p[kz * (112 * FC1_OUT) + m * FC1_OUT + n] = acc[r];
    }
}

// ---- fc2 + log_softmax fused; sums 2 fc1 partials, applies fc1 bias+ELU ----
__global__ void fc2_lsm(const float* __restrict__ z1p, const float* __restrict__ fc1b,
                        const float* __restrict__ w, const float* __restrict__ fc2b,
                        float* __restrict__ out) {
    int b = blockIdx.x;
    int t = threadIdx.x;
    int wv = t >> 6;
    int lane = t & 63;
    float acc = 0.f;
#pragma unroll
    for (int m = 0; m < 8; m++) {
        int k = lane * 8 + m;
        float xv = fc1b[k] + z1p[b * FC1_OUT + k] + z1p[112 * FC1_OUT + b * FC1_OUT + k];
        xv = xv > 0.f ? xv : expm1f(xv);
        acc += xv * w[k * 10 + wv];
    }
#pragma unroll
    for (int off = 32; off > 0; off >>= 1) acc += __shfl_down(acc, off);
    __shared__ float zs[10];
    if (lane == 0) {
        float z = acc + fc2b[wv];
        zs[wv] = z > 0.f ? z : expm1f(z);
    }
    __syncthreads();
    if (t < 10) {
        float m = -1e30f;
        for (int jj = 0; jj < 10; jj++) m = fmaxf(m, zs[jj]);
        float s = 0.f;
        for (int jj = 0; jj < 10; jj++) s += expf(zs[jj] - m);
        out[b * 10 + t] = zs[t] - m - logf(s);
    }
}

extern "C" void kernel_launch(void* const* d_in, const int* in_sizes, int n_in,
                              void* d_out, int out_size, void* d_ws, size_t ws_size,
                              hipStream_t stream) {
    const float* x     = (const float*)d_in[0];
    const float* ps0   = (const float*)d_in[1];
    const float* ps1   = (const float*)d_in[2];
    const float* W1    = (const float*)d_in[3];
    const float* root1 = (const float*)d_in[4];
    const float* b1    = (const float*)d_in[5];
    const float* W2    = (const float*)d_in[6];
    const float* root2 = (const float*)d_in[7];
    const float* b2v   = (const float*)d_in[8];
    const float* fc1w  = (const float*)d_in[9];
    const float* fc1b  = (const float*)d_in[10];
    const float* fc2w  = (const float*)d_in[11];
    const float* fc2b  = (const float*)d_in[12];
    const int*   ei0   = (const int*)d_in[13];
    const int*   ei1   = (const int*)d_in[14];

    float* ws = (float*)d_ws;
    int* gcur  = (int*)ws;                         //        383  (memset region)
    int* db    = (int*)(ws + 384);                 //        383
    int* off   = (int*)(ws + 768);                 //     98,001
    int* pk    = (int*)(ws + 98772);               //    919,200 (383 x 2400)
    int* idxx  = (int*)(ws + 1017972);             //    784,000
    float* p1  = ws + 1801972;                     //    627,200
    float* h2  = ws + 2429172;                     //  1,254,400
    unsigned short* p2b = (unsigned short*)(ws + 3683572);  // 175,616 w
    float* z1p = ws + 3859188;                     //    114,688
    unsigned short* w2t = (unsigned short*)(ws + 3973876);  // 26,624 w
    unsigned short* wt1 = (unsigned short*)(ws + 4000500);  // 802,816 w
    // high water: 4,803,316 words = 19.2 MB

    hipMemsetAsync(gcur, 0, (size_t)NCOARSE * sizeof(int), stream);

    coarse_bin<<<(E0 + E1 + 4095) / 4096, 512, 0, stream>>>(ei0, ei1, gcur, pk);
    tiny_scan<<<1, 512, 0, stream>>>(gcur, db, off);
    fine_sort<<<NCOARSE, 256, 0, stream>>>(pk, gcur, db, idxx, off);
    prep_weights<<<dim3(50, 8), 256, 0, stream>>>(fc1w, W2, root2, wt1, w2t);
    conv1_pool<<<1400, 256, 0, stream>>>(idxx, off, x, ei0, ps0,
                                         W1, root1, b1, p1);
    conv2_fused<<<N1 / 8, 256, 0, stream>>>(p1, idxx, off, ei1, ps1, w2t, b2v, h2);
    pool2b<<<(112 * FC1_IN + 255) / 256, 256, 0, stream>>>(h2, p2b);
    gemm_fc1<<<dim3(8, 7, 2), 256, 0, stream>>>(p2b, wt1, z1p);
    fc2_lsm<<<BSZ, 640, 0, stream>>>(z1p, fc1b, fc2w, fc2b, (float*)d_out);
}

// Round 18
// 218.670 us; speedup vs baseline: 1.0429x; 1.0429x over previous
//
#include <hip/hip_runtime.h>
#include <hip/hip_bf16.h>

#define KK 5
constexpr int N0 = 78400;     // B*28*28
constexpr int E0 = 627200;    // N0*8
constexpr int N1 = 19600;     // B*14*14
constexpr int E1 = 156800;    // N1*8
constexpr int C1 = 32, C2 = 64;
constexpr int BSZ = 100;
constexpr int FC1_IN = 3136, FC1_OUT = 512;
constexpr int NKEYS = 98000;  // N0 + N1 global node keys
constexpr int NCOARSE = 383;  // coarse buckets of 256 keys
constexpr int CAPB = 2400;    // bucket capacity: Poisson(2048) + 7.7 sigma
constexpr int KEXT = 832;     // 800 tap-space + 32 root channels
constexpr int ULS = 836;      // LDS fp32 U row stride
constexpr int UBS = 856;      // LDS bf16 U row stride (ushorts)
constexpr int CH2 = 160;      // conv2 edge staging chunk
constexpr int CH1 = 640;      // conv1 edge staging chunk

typedef __attribute__((ext_vector_type(8))) short bf16x8;
typedef __attribute__((ext_vector_type(4))) float f32x4;

__device__ __forceinline__ unsigned short f2bf(float f) {
    union { float f; unsigned u; } v; v.f = f;
    unsigned u = v.u;
    unsigned r = (u + 0x7FFF + ((u >> 16) & 1)) >> 16;   // RNE
    return (unsigned short)r;
}

__device__ __forceinline__ void taps4(float px, float py,
                                      int& a00, int& a01, int& a10, int& a11,
                                      float& fx, float& fy) {
    float kfx = floorf(px), kfy = floorf(py);
    fx = px - kfx; fy = py - kfy;
    int k0x = min(max((int)kfx, 0), KK - 1);
    int k0y = min(max((int)kfy, 0), KK - 1);
    int k1x = min(k0x + 1, KK - 1), k1y = min(k0y + 1, KK - 1);
    a00 = k0x * KK + k0y; a01 = k0x * KK + k1y;
    a10 = k1x * KK + k0y; a11 = k1x * KK + k1y;
}

// ---- sort A + weight prep merged. Blocks 0..191: LDS-histogram coarse
//      binning (packed {id|lowkey<<20} runs). Blocks 192..583: wt1 transpose
//      tiles. Blocks 584..591: w2t. One launch, prep rides under sort latency.
__global__ void coarse_bin(const int* __restrict__ ei0, const int* __restrict__ ei1,
                           int* __restrict__ gcur, int* __restrict__ pk,
                           const float* __restrict__ fc1w, const float* __restrict__ W2,
                           const float* __restrict__ root2,
                           unsigned short* __restrict__ wt1,
                           unsigned short* __restrict__ w2t) {
    __shared__ int hist[NCOARSE];
    __shared__ int gbase[NCOARSE];
    __shared__ unsigned short tile[64 * 66];
    int t = threadIdx.x;               // 512 threads
    if (blockIdx.x >= 192) {
        int pb = blockIdx.x - 192;
        if (pb >= 392) {               // w2t: 8 blocks x 6656 elems
            int base = (pb - 392) * 6656;
            for (int i2 = t; i2 < 6656; i2 += 512) {
                int idx = base + i2;
                int o = idx / KEXT, k = idx - o * KEXT;
                float v = (k < 800) ? W2[k * 64 + o] : root2[(k - 800) * 64 + o];
                w2t[idx] = f2bf(v);
            }
            return;
        }
        // wt1 transpose: 392 blocks = 49 k-tiles x 8 j-tiles
        int k0 = (pb >> 3) * 64, j0 = (pb & 7) * 64;
        int jj = t & 63, ks = t >> 6;  // ks 0..7
        for (int kk = ks; kk < 64; kk += 8)
            tile[kk * 66 + jj] = f2bf(fc1w[(k0 + kk) * FC1_OUT + j0 + jj]);
        __syncthreads();
        int kk2 = t & 63, js = t >> 6;
        for (int j2 = js; j2 < 64; j2 += 8)
            wt1[(j0 + j2) * FC1_IN + k0 + kk2] = tile[kk2 * 66 + j2];
        return;
    }
    for (int i = t; i < NCOARSE; i += 512) hist[i] = 0;
    __syncthreads();
    int e0b = blockIdx.x * 4096;
    int ids[8], keys[8], rnk[8];
#pragma unroll
    for (int j = 0; j < 8; j++) {
        int e = e0b + t + j * 512;
        int gk = -1, id = 0;
        if (e < E0) { gk = ei0[E0 + e]; id = e; }
        else if (e < E0 + E1) { int el = e - E0; gk = N0 + ei1[E1 + el]; id = el; }
        ids[j] = id; keys[j] = gk;
    }
#pragma unroll
    for (int j = 0; j < 8; j++)
        if (keys[j] >= 0) rnk[j] = atomicAdd(&hist[keys[j] >> 8], 1);  // native ds_add
    __syncthreads();
    for (int i = t; i < NCOARSE; i += 512)
        gbase[i] = hist[i] ? atomicAdd(&gcur[i], hist[i]) : 0;
    __syncthreads();
#pragma unroll
    for (int j = 0; j < 8; j++) {
        if (keys[j] >= 0) {
            int b = keys[j] >> 8;
            int p = gbase[b] + rnk[j];
            if (p < CAPB) pk[b * CAPB + p] = ids[j] | ((keys[j] & 255) << 20);
        }
    }
}

// ---- sort C: per-bucket LDS counting sort -> dense idxx + off.
//      Each block computes its own dense base (no tiny_scan kernel). ----
__global__ void fine_sort(const int* __restrict__ pk, const int* __restrict__ gcur,
                          int* __restrict__ idxx, int* __restrict__ off) {
    __shared__ int cl[NCOARSE];    // 1.5 KB
    __shared__ int ent[CAPB];
    __shared__ int rnk[CAPB];
    __shared__ int h2[256];
    __shared__ int sc[256];
    __shared__ int redbuf[4];
    __shared__ int baseS;
    int b = blockIdx.x, t = threadIdx.x;   // 256 threads
    for (int i2 = t; i2 < NCOARSE; i2 += 256) cl[i2] = min(gcur[i2], CAPB);
    __syncthreads();
    {   // base = sum cl[0..b-1], 256-thread reduce
        int s = 0;
        if (t < b) s += cl[t];
        if (t + 256 < b) s += cl[t + 256];
#pragma unroll
        for (int o2 = 32; o2 > 0; o2 >>= 1) s += __shfl_down(s, o2);
        if ((t & 63) == 0) redbuf[t >> 6] = s;
        __syncthreads();
        if (t == 0) baseS = redbuf[0] + redbuf[1] + redbuf[2] + redbuf[3];
        __syncthreads();
    }
    int base = baseS;
    int cb = cl[b];
    h2[t] = 0;
    __syncthreads();
    for (int i = t; i < cb; i += 256) {
        int v = pk[b * CAPB + i];
        ent[i] = v;
        rnk[i] = atomicAdd(&h2[(v >> 20) & 255], 1);   // native ds_add
    }
    __syncthreads();
    int v0 = h2[t];
    sc[t] = v0;
    __syncthreads();
    for (int d = 1; d < 256; d <<= 1) {
        int add = (t >= d) ? sc[t - d] : 0;
        __syncthreads();
        sc[t] += add;
        __syncthreads();
    }
    int excl = sc[t] - v0;
    __syncthreads();
    sc[t] = excl;
    __syncthreads();
    int n = (b << 8) + t;
    if (n < NKEYS) off[n] = base + excl;
    if (b == 0 && t == 0) off[NKEYS] = E0 + E1;
    for (int i = t; i < cb; i += 256) {
        int v = ent[i];
        idxx[base + sc[(v >> 20) & 255] + rnk[i]] = v & 0xFFFFF;
    }
}

// ---- conv1 + pool1 fused: block = 2 image rows (56 nodes). ----
__global__ __launch_bounds__(256, 4)
void conv1_pool(const int* __restrict__ idxx, const int* __restrict__ off,
                const float* __restrict__ x, const int* __restrict__ ei0,
                const float* __restrict__ ps0, const float* __restrict__ W1,
                const float* __restrict__ root, const float* __restrict__ bias,
                float* __restrict__ p1) {
    __shared__ float S4[224 * 25];    // 22.4 KB quadrant slices; h1 tile aliases
    __shared__ float Sr[56 * 25];     // 5.6 KB reduced
    __shared__ float exv[CH1], efx[CH1], efy[CH1];
    __shared__ int   emt[CH1];
    float* h1t = S4;
    int t = threadIdx.x;
    int bb = blockIdx.x;              // 1400 blocks; nodes bb*56 .. +55
    int n0 = bb * 56;
    int q = t & 3, nl = t >> 2;
    bool actN = nl < 56;
    int n = n0 + (actN ? nl : 0);
    float* sp = S4 + (actN ? (nl * 4 + q) : 0) * 25;
    for (int i = t; i < 224 * 25; i += 256) S4[i] = 0.f;
    int e0 = off[n0], e1 = off[n0 + 56];
    int my0 = off[n], my1 = off[n + 1];
    for (int base = e0; base < e1; base += CH1) {
        int nE = min(e1 - base, CH1);
        __syncthreads();
        for (int j = t; j < nE; j += 256) {
            int e = idxx[base + j];
            int src = ei0[e];
            int a00, a01, a10, a11; float fx, fy;
            taps4(ps0[2 * e] * (KK - 1), ps0[2 * e + 1] * (KK - 1),
                  a00, a01, a10, a11, fx, fy);
            emt[j] = a00 | (a01 << 5) | (a10 << 10) | (a11 << 15);
            efx[j] = fx; efy[j] = fy;
            exv[j] = x[src];
        }
        __syncthreads();
        if (actN) {
            int r0 = max(my0 - base, 0), r1 = min(my1 - base, nE);
            for (int p = r0 + q; p < r1; p += 4) {
                float xv = exv[p]; int m = emt[p];
                float fx = efx[p], fy = efy[p];
                float gx = 1.f - fx, gy = 1.f - fy;
                sp[m & 31]         += gx * gy * xv;
                sp[(m >> 5) & 31]  += gx * fy * xv;
                sp[(m >> 10) & 31] += fx * gy * xv;
                sp[(m >> 15) & 31] += fx * fy * xv;
            }
        }
    }
    __syncthreads();
    for (int i2 = t; i2 < 56 * 25; i2 += 256) {
        int n2 = i2 / 25, a = i2 - n2 * 25;
        Sr[i2] = S4[(n2 * 4 + 0) * 25 + a] + S4[(n2 * 4 + 1) * 25 + a] +
                 S4[(n2 * 4 + 2) * 25 + a] + S4[(n2 * 4 + 3) * 25 + a];
    }
    __syncthreads();
    {
        int o = t & 31, ng = t >> 5;
        float w1c[25];
#pragma unroll
        for (int a = 0; a < 25; a++) w1c[a] = W1[a * C1 + o];
        float ro = root[o], bo = bias[o];
        for (int j2 = 0; j2 < 7; j2++) {
            int nl2 = ng * 7 + j2;
            int n2 = n0 + nl2;
            float acc = 0.f;
#pragma unroll
            for (int a = 0; a < 25; a++) acc += Sr[nl2 * 25 + a] * w1c[a];
            float invd = 1.f / fmaxf((float)(off[n2 + 1] - off[n2]), 1.f);
            float v = acc * invd + x[n2] * ro + bo;
            h1t[nl2 * 32 + o] = v > 0.f ? v : expm1f(v);
        }
    }
    __syncthreads();
    for (int i2 = t; i2 < 448; i2 += 256) {
        int o2 = i2 & 31, pc = i2 >> 5;
        float m0 = h1t[(2 * pc) * 32 + o2],      m1 = h1t[(2 * pc + 1) * 32 + o2];
        float m2 = h1t[(28 + 2 * pc) * 32 + o2], m3 = h1t[(28 + 2 * pc + 1) * 32 + o2];
        p1[(bb * 14 + pc) * C1 + o2] = fmaxf(fmaxf(m0, m1), fmaxf(m2, m3));
    }
}

// ---- conv2 fused (MFMA): 8 nodes/block, 5 blocks/CU.
//  Phase1: edge loop unrolled x2 with BOTH p1 loads issued before use
//  (2 outstanding loads -> MLP on the random-gather latency). ----
__global__ __launch_bounds__(256, 5)
void conv2_fused(const float* __restrict__ p1, const int* __restrict__ idxx,
                 const int* __restrict__ off, const int* __restrict__ ei1,
                 const float* __restrict__ ps1,
                 const unsigned short* __restrict__ w2t,
                 const float* __restrict__ b2, float* __restrict__ h2) {
    __shared__ float Ul[8 * ULS];           // 26.8 KB (bf16 view aliases this)
    __shared__ int   es[CH2];
    __shared__ int   et[CH2];
    __shared__ float efx[CH2], efy[CH2];
    unsigned short* Ub = (unsigned short*)Ul;
    int t = threadIdx.x;
    int nb = blockIdx.x * 8;
    int i = t & 31, g = t >> 5;
    float* up = Ul + g * ULS;
#pragma unroll
    for (int a = 0; a < 25; a++) up[a * 32 + i] = 0.f;
    up[800 + i] = p1[(nb + g) * C1 + i];
    int e0 = off[N0 + nb], e1 = off[N0 + nb + 8];
    int my0 = off[N0 + nb + g], my1 = off[N0 + nb + g + 1];
    for (int base = e0; base < e1; base += CH2) {
        int nE = min(e1 - base, CH2);
        __syncthreads();
        for (int j = t; j < nE; j += 256) {
            int e = idxx[base + j];
            es[j] = ei1[e];
            int a00, a01, a10, a11; float fx, fy;
            taps4(ps1[2 * e] * (KK - 1), ps1[2 * e + 1] * (KK - 1),
                  a00, a01, a10, a11, fx, fy);
            et[j] = a00 | (a01 << 5) | (a10 << 10) | (a11 << 15);
            efx[j] = fx; efy[j] = fy;
        }
        __syncthreads();
        int r0 = max(my0 - base, 0);
        int r1 = min(my1 - base, nE);
        int myT = max(r1 - r0, 0);
        int m64 = max(myT, __shfl_xor(myT, 32));   // wave-uniform trip count
        for (int jj = 0; jj < m64; jj += 2) {
            bool a0 = jj < myT, a1 = jj + 1 < myT;
            int j0 = a0 ? r0 + jj : 0, j1 = a1 ? r0 + jj + 1 : 0;
            int s0 = es[j0], s1 = es[j1];
            int mm0 = et[j0], mm1 = et[j1];
            float fx0 = efx[j0], fy0 = efy[j0];
            float fx1 = efx[j1], fy1 = efy[j1];
            float x0 = p1[s0 * C1 + i];     // both loads issued before either use
            float x1 = p1[s1 * C1 + i];
            if (a0) {
                float gx = 1.f - fx0, gy = 1.f - fy0;
                up[(mm0 & 31) * 32 + i]         += gx * gy * x0;
                up[((mm0 >> 5) & 31) * 32 + i]  += gx * fy0 * x0;
                up[((mm0 >> 10) & 31) * 32 + i] += fx0 * gy * x0;
                up[((mm0 >> 15) & 31) * 32 + i] += fx0 * fy0 * x0;
            }
            if (a1) {
                float gx = 1.f - fx1, gy = 1.f - fy1;
                up[(mm1 & 31) * 32 + i]         += gx * gy * x1;
                up[((mm1 >> 5) & 31) * 32 + i]  += gx * fy1 * x1;
                up[((mm1 >> 10) & 31) * 32 + i] += fx1 * gy * x1;
                up[((mm1 >> 15) & 31) * 32 + i] += fx1 * fy1 * x1;
            }
        }
    }
    __syncthreads();
    // phase 1.5: fp32 -> bf16 once (invd folded into tap part)
    {
        int g2 = t >> 5, ks = (t & 31) * 26;
        int dgc = off[N0 + nb + g2 + 1] - off[N0 + nb + g2];
        float invd = 1.f / fmaxf((float)dgc, 1.f);
        const float* srcp = Ul + g2 * ULS + ks;
        float rv[26];
#pragma unroll
        for (int j = 0; j < 26; j++) {
            float v = srcp[j];
            rv[j] = (ks + j < 800) ? v * invd : v;
        }
        __syncthreads();
        unsigned* dstp = (unsigned*)(Ub + g2 * UBS + ks);
#pragma unroll
        for (int j = 0; j < 13; j++) {
            unsigned lo = f2bf(rv[2 * j]), hi = f2bf(rv[2 * j + 1]);
            dstp[j] = lo | (hi << 16);
        }
    }
    __syncthreads();
    // phase 2: MFMA. D[node=quad*4+r][o=lane&15]; A rows 8-15 alias 0-7
    int wv = t >> 6, lane = t & 63, quad = lane >> 4, lrow = lane & 15;
    f32x4 acc = {0.f, 0.f, 0.f, 0.f};
    int nodeA = lrow & 7;
    const unsigned short* bbase = w2t + (wv * 16 + lrow) * KEXT;
    const unsigned short* abase = Ub + nodeA * UBS;
#pragma unroll
    for (int kc = 0; kc < 26; kc++) {
        bf16x8 a = *(const bf16x8*)(abase + kc * 32 + quad * 8);
        bf16x8 b = *(const bf16x8*)(bbase + kc * 32 + quad * 8);
        acc = __builtin_amdgcn_mfma_f32_16x16x32_bf16(a, b, acc, 0, 0, 0);
    }
    if (quad < 2) {
        int o = wv * 16 + lrow;
        float bo = b2[o];
#pragma unroll
        for (int r = 0; r < 4; r++) {
            int node = quad * 4 + r;
            float v = acc[r] + bo;
            v = v > 0.f ? v : expm1f(v);
            h2[(nb + node) * C2 + o] = v;
        }
    }
}

// ---- pool2 -> bf16 [112 x 3136], rows 100..111 zeroed (M-pad for MFMA) ----
__global__ void pool2b(const float* __restrict__ h2, unsigned short* __restrict__ p2b) {
    int idx = blockIdx.x * blockDim.x + threadIdx.x;
    if (idx >= 112 * FC1_IN) return;
    if (idx >= 100 * FC1_IN) { p2b[idx] = 0; return; }
    int o = idx & 63; int t2 = idx >> 6;
    int c = t2 % 14; int r = (t2 / 14) % 14; int b = t2 / 196;
    const float* base = h2 + (((b * 28 + 2 * r) * 28 + 2 * c) * C2 + o);
    float m = fmaxf(fmaxf(base[0], base[C2]),
                    fmaxf(base[28 * C2], base[28 * C2 + C2]));
    p2b[idx] = f2bf(m);
}

// ---- fc1 MFMA: [112,3136]bf16 @ wt1^T -> z1p fp32 partials (2 kz). ----
__global__ void gemm_fc1(const unsigned short* __restrict__ p2b,
                         const unsigned short* __restrict__ wt1,
                         float* __restrict__ z1p) {
    constexpr int AS = 232;
    __shared__ unsigned short as_[16 * AS];
    int t = threadIdx.x;
    int jt = blockIdx.x, mt = blockIdx.y, kz = blockIdx.z;
    int wv = t >> 6, lane = t & 63, quad = lane >> 4, lrow = lane & 15;
    int m0 = mt * 16;
    int kbase = kz * 1568;
    const unsigned short* bbase = wt1 + (jt * 64 + wv * 16 + lrow) * FC1_IN + kbase;
    f32x4 acc = {0.f, 0.f, 0.f, 0.f};
    for (int ch = 0; ch < 7; ch++) {
        __syncthreads();
        for (int slot = t; slot < 448; slot += 256) {
            int r = slot / 28, c = slot - (slot / 28) * 28;
            *(uint4*)(as_ + r * AS + c * 8) =
                *(const uint4*)(p2b + (m0 + r) * FC1_IN + kbase + ch * 224 + c * 8);
        }
        __syncthreads();
        const unsigned short* ab = as_ + lrow * AS;
        const unsigned short* bb = bbase + ch * 224;
#pragma unroll
        for (int kk = 0; kk < 7; kk++) {
            bf16x8 a = *(const bf16x8*)(ab + kk * 32 + quad * 8);
            bf16x8 b = *(const bf16x8*)(bb + kk * 32 + quad * 8);
            acc = __builtin_amdgcn_mfma_f32_16x16x32_bf16(a, b, acc, 0, 0, 0);
        }
    }
    int n = jt * 64 + wv * 16 + lrow;
#pragma unroll
    for (int r = 0; r < 4; r++) {
        int m = m0 + quad * 4 + r;
        z1p[kz * (112 * FC1_OUT) + m * FC1_OUT + n] = acc[r];
    }
}

// ---- fc2 + log_softmax fused; sums 2 fc1 partials, applies fc1 bias+ELU ----
__global__ void fc2_lsm(const float* __restrict__ z1p, const float* __restrict__ fc1b,
                        const float* __restrict__ w, const float* __restrict__ fc2b,
                        float* __restrict__ out) {
    int b = blockIdx.x;
    int t = threadIdx.x;
    int wv = t >> 6;
    int lane = t & 63;
    float acc = 0.f;
#pragma unroll
    for (int m = 0; m < 8; m++) {
        int k = lane * 8 + m;
        float xv = fc1b[k] + z1p[b * FC1_OUT + k] + z1p[112 * FC1_OUT + b * FC1_OUT + k];
        xv = xv > 0.f ? xv : expm1f(xv);
        acc += xv * w[k * 10 + wv];
    }
#pragma unroll
    for (int off = 32; off > 0; off >>= 1) acc += __shfl_down(acc, off);
    __shared__ float zs[10];
    if (lane == 0) {
        float z = acc + fc2b[wv];
        zs[wv] = z > 0.f ? z : expm1f(z);
    }
    __syncthreads();
    if (t < 10) {
        float m = -1e30f;
        for (int jj = 0; jj < 10; jj++) m = fmaxf(m, zs[jj]);
        float s = 0.f;
        for (int jj = 0; jj < 10; jj++) s += expf(zs[jj] - m);
        out[b * 10 + t] = zs[t] - m - logf(s);
    }
}

extern "C" void kernel_launch(void* const* d_in, const int* in_sizes, int n_in,
                              void* d_out, int out_size, void* d_ws, size_t ws_size,
                              hipStream_t stream) {
    const float* x     = (const float*)d_in[0];
    const float* ps0   = (const float*)d_in[1];
    const float* ps1   = (const float*)d_in[2];
    const float* W1    = (const float*)d_in[3];
    const float* root1 = (const float*)d_in[4];
    const float* b1    = (const float*)d_in[5];
    const float* W2    = (const float*)d_in[6];
    const float* root2 = (const float*)d_in[7];
    const float* b2v   = (const float*)d_in[8];
    const float* fc1w  = (const float*)d_in[9];
    const float* fc1b  = (const float*)d_in[10];
    const float* fc2w  = (const float*)d_in[11];
    const float* fc2b  = (const float*)d_in[12];
    const int*   ei0   = (const int*)d_in[13];
    const int*   ei1   = (const int*)d_in[14];

    float* ws = (float*)d_ws;
    int* gcur  = (int*)ws;                         //        383  (memset region)
    int* off   = (int*)(ws + 384);                 //     98,001
    int* pk    = (int*)(ws + 98388);               //    919,200 (383 x 2400)
    int* idxx  = (int*)(ws + 1017588);             //    784,000
    float* p1  = ws + 1801588;                     //    627,200
    float* h2  = ws + 2428788;                     //  1,254,400
    unsigned short* p2b = (unsigned short*)(ws + 3683188);  // 175,616 w
    float* z1p = ws + 3858804;                     //    114,688
    unsigned short* w2t = (unsigned short*)(ws + 3973492);  // 26,624 w
    unsigned short* wt1 = (unsigned short*)(ws + 4000116);  // 802,816 w
    // high water: 4,802,932 words = 19.2 MB

    hipMemsetAsync(gcur, 0, (size_t)NCOARSE * sizeof(int), stream);

    coarse_bin<<<592, 512, 0, stream>>>(ei0, ei1, gcur, pk, fc1w, W2, root2, wt1, w2t);
    fine_sort<<<NCOARSE, 256, 0, stream>>>(pk, gcur, idxx, off);
    conv1_pool<<<1400, 256, 0, stream>>>(idxx, off, x, ei0, ps0,
                                         W1, root1, b1, p1);
    conv2_fused<<<N1 / 8, 256, 0, stream>>>(p1, idxx, off, ei1, ps1, w2t, b2v, h2);
    pool2b<<<(112 * FC1_IN + 255) / 256, 256, 0, stream>>>(h2, p2b);
    gemm_fc1<<<dim3(8, 7, 2), 256, 0, stream>>>(p2b, wt1, z1p);
    fc2_lsm<<<BSZ, 640, 0, stream>>>(z1p, fc1b, fc2w, fc2b, (float*)d_out);
}